// Round 1
// baseline (498.466 us; speedup 1.0000x reference)
//
#include <hip/hip_runtime.h>

typedef unsigned int u32;
typedef unsigned short u16;
typedef __attribute__((ext_vector_type(8))) __bf16 bf16x8;
typedef __attribute__((ext_vector_type(4))) float f32x4;

#define T_   16
#define HH   32
#define WW   32
#define HEADS_ 8
#define HD_  64
#define CC   512
#define NPOS 16384
#define CQKV 1536

__device__ __forceinline__ u16 f2bf(float f){
  u32 u = __builtin_bit_cast(u32, f);
  u32 r = u + 0x7FFFu + ((u >> 16) & 1u);
  return (u16)(r >> 16);
}

__device__ __forceinline__ void gload16(const void* g, void* l){
  __builtin_amdgcn_global_load_lds(
    (const __attribute__((address_space(1))) void*)g,
    (__attribute__((address_space(3))) void*)l, 16, 0, 0);
}

// ---- convert x (fp32 -> bf16), 8 elems/thread -------------------------------
__global__ __launch_bounds__(256) void k_convert_x(const float* __restrict__ x,
                                                   u16* __restrict__ xb){
  int i = blockIdx.x * 256 + threadIdx.x;       // 0 .. 1048575
  const float4 a = ((const float4*)x)[i*2];
  const float4 b = ((const float4*)x)[i*2+1];
  union { u16 h[8]; uint4 q; } o;
  o.h[0]=f2bf(a.x); o.h[1]=f2bf(a.y); o.h[2]=f2bf(a.z); o.h[3]=f2bf(a.w);
  o.h[4]=f2bf(b.x); o.h[5]=f2bf(b.y); o.h[6]=f2bf(b.z); o.h[7]=f2bf(b.w);
  ((uint4*)xb)[i] = o.q;
}

// ---- weights: Wt[n][k] = w_*[k][n&511] (qkv concat), Wot[n][k] = w_o[k][n] --
__global__ __launch_bounds__(256) void k_convert_w(const float* __restrict__ wq,
                                                   const float* __restrict__ wk,
                                                   const float* __restrict__ wv,
                                                   const float* __restrict__ wo,
                                                   u16* __restrict__ wt,
                                                   u16* __restrict__ wot){
  int i = blockIdx.x * 256 + threadIdx.x;       // 0 .. 1048575
  if (i < 1536*512){
    int n = i >> 9, k = i & 511;
    const float* src = (n < 512) ? wq : (n < 1024) ? wk : wv;
    wt[i] = f2bf(src[k*512 + (n & 511)]);
  } else {
    int j = i - 1536*512;
    int n = j >> 9, k = j & 511;
    wot[j] = f2bf(wo[k*512 + n]);
  }
}

// ---- bf16 MFMA GEMM, A[M,K] x Bt[N,K]^T -> C[M,N]. 128x128 tile, BK=32 ------
// OUTMODE 0: bf16 out, no bias.  OUTMODE 1: fp32 out + bias.
template<int OUTMODE>
__global__ __launch_bounds__(256) void k_gemm_bt(
    const u16* __restrict__ A, const u16* __restrict__ Bt,
    void* __restrict__ C, const float* __restrict__ bias,
    int M, int N, int K)
{
  __shared__ u16 lds[2][2][128*32];     // [buf][A/B][row*32 + k] (swizzled granules)
  const int tid = threadIdx.x;
  const int lane = tid & 63;
  const int l15 = lane & 15, lhi = lane >> 4;
  const int wv = tid >> 6;
  const int tm = blockIdx.y * 128, tn = blockIdx.x * 128;
  const int wm = (wv >> 1) * 64, wn = (wv & 1) * 64;
  const int nk = K >> 5;

  auto stage = [&](int buf, int kb){
    #pragma unroll
    for (int half = 0; half < 2; ++half){
      int c = tid + half*256;                 // 16B chunk id, 512 per matrix
      int row = c >> 2;
      int g = (c & 3) ^ ((c >> 3) & 3);       // inverse of read-side swizzle
      char* la = (char*)(&lds[buf][0][0]) + ((c >> 6) << 10);
      gload16(A + (size_t)(tm + row) * K + (kb << 5) + (g << 3), la);
      char* lb = (char*)(&lds[buf][1][0]) + ((c >> 6) << 10);
      gload16(Bt + (size_t)(tn + row) * K + (kb << 5) + (g << 3), lb);
    }
  };

  stage(0, 0);
  f32x4 acc[4][4];
  const f32x4 z4 = {0.f, 0.f, 0.f, 0.f};
  #pragma unroll
  for (int i = 0; i < 4; ++i)
    #pragma unroll
    for (int j = 0; j < 4; ++j) acc[i][j] = z4;
  __syncthreads();

  int buf = 0;
  for (int kb = 0; kb < nk; ++kb){
    if (kb + 1 < nk) stage(buf ^ 1, kb + 1);
    const char* la = (const char*)(&lds[buf][0][0]);
    const char* lb = (const char*)(&lds[buf][1][0]);
    bf16x8 af[4], bfr[4];
    #pragma unroll
    for (int ai = 0; ai < 4; ++ai){
      int row = wm + ai*16 + l15;
      af[ai] = *(const bf16x8*)(la + row*64 + ((lhi ^ ((row >> 1) & 3)) << 4));
    }
    #pragma unroll
    for (int bj = 0; bj < 4; ++bj){
      int row = wn + bj*16 + l15;
      bfr[bj] = *(const bf16x8*)(lb + row*64 + ((lhi ^ ((row >> 1) & 3)) << 4));
    }
    #pragma unroll
    for (int ai = 0; ai < 4; ++ai)
      #pragma unroll
      for (int bj = 0; bj < 4; ++bj)
        acc[ai][bj] = __builtin_amdgcn_mfma_f32_16x16x32_bf16(af[ai], bfr[bj], acc[ai][bj], 0, 0, 0);
    __syncthreads();
    buf ^= 1;
  }

  #pragma unroll
  for (int ai = 0; ai < 4; ++ai)
    #pragma unroll
    for (int bj = 0; bj < 4; ++bj)
      #pragma unroll
      for (int r = 0; r < 4; ++r){
        int rr = tm + wm + ai*16 + (lhi << 2) + r;
        int cc = tn + wn + bj*16 + l15;
        float v = acc[ai][bj][r];
        if (OUTMODE == 0) ((u16*)C)[(size_t)rr * N + cc] = f2bf(v);
        else              ((float*)C)[(size_t)rr * N + cc] = v + bias[cc];
      }
}

// ---- V^T: Vt[ch][m] = QKV[m][1024+ch], tiled 64x64 transpose ----------------
__global__ __launch_bounds__(256) void k_vt(const u16* __restrict__ qkv,
                                            u16* __restrict__ vt){
  __shared__ u16 tl[64][65];
  const int tid = threadIdx.x;
  const int m0 = blockIdx.y << 6, c0 = blockIdx.x << 6;
  #pragma unroll
  for (int i = 0; i < 16; ++i){
    int idx = tid + (i << 8);
    int r = idx >> 6, c = idx & 63;
    tl[r][c] = qkv[(size_t)(m0 + r) * CQKV + 1024 + c0 + c];
  }
  __syncthreads();
  #pragma unroll
  for (int i = 0; i < 16; ++i){
    int idx = tid + (i << 8);
    int d = idx >> 6, mm = idx & 63;
    vt[((size_t)(c0 + d) << 14) + m0 + mm] = tl[mm][d];
  }
}

// ---- neighborhood attention: 1 block per (h,w), wave = head -----------------
__global__ __launch_bounds__(512) void k_attn(const u16* __restrict__ qkv,
                                              const u16* __restrict__ vt,
                                              u16* __restrict__ ao){
  __shared__ u16 pbuf[HEADS_][16][16];
  const int tid = threadIdx.x;
  const int lane = tid & 63;
  const int hd  = tid >> 6;
  const int l15 = lane & 15, lhi = lane >> 4;
  const int hw = blockIdx.x;
  const int h = hw >> 5, w = hw & 31;
  const int hs = min(max(h - 3, 0), HH - 7);
  const int ws = min(max(w - 3, 0), WW - 7);

  // Q A-fragments: row t = l15, k = d = lhi*8 + j (+32 for second frag)
  const size_t qoff = ((size_t)hw * 16 + l15) * CQKV + hd * HD_;
  const bf16x8 qa0 = *(const bf16x8*)(qkv + qoff + (lhi << 3));
  const bf16x8 qa1 = *(const bf16x8*)(qkv + qoff + 32 + (lhi << 3));

  float mrun[4], lpart[4];
  f32x4 oacc[4];
  const f32x4 z4 = {0.f,0.f,0.f,0.f};
  bool val[4];
  #pragma unroll
  for (int r = 0; r < 4; ++r){
    mrun[r] = -3.0e38f; lpart[r] = 0.f;
    int t = (lhi << 2) + r;
    int tst = min(max(t - 3, 0), T_ - 7);
    val[r] = (l15 >= tst) && (l15 < tst + 7);   // col t' = l15 inside t-window
  }
  #pragma unroll
  for (int c = 0; c < 4; ++c) oacc[c] = z4;

  for (int jh = 0; jh < 7; ++jh){
    for (int jw = 0; jw < 7; ++jw){
      const int sb = (((hs + jh) << 5) + (ws + jw)) << 4;   // key row base (16 t' rows)
      const size_t koff = (size_t)(sb + l15) * CQKV + CC + hd * HD_;
      bf16x8 kb0 = *(const bf16x8*)(qkv + koff + (lhi << 3));
      bf16x8 kb1 = *(const bf16x8*)(qkv + koff + 32 + (lhi << 3));
      f32x4 s = z4;
      s = __builtin_amdgcn_mfma_f32_16x16x32_bf16(qa0, kb0, s, 0, 0, 0);
      s = __builtin_amdgcn_mfma_f32_16x16x32_bf16(qa1, kb1, s, 0, 0, 0);
      // S: row t = lhi*4+r, col t' = l15. Mask + online softmax.
      #pragma unroll
      for (int r = 0; r < 4; ++r){
        float sv = val[r] ? s[r] : -1.0e30f;
        float tmax = sv;
        tmax = fmaxf(tmax, __shfl_xor(tmax, 1));
        tmax = fmaxf(tmax, __shfl_xor(tmax, 2));
        tmax = fmaxf(tmax, __shfl_xor(tmax, 4));
        tmax = fmaxf(tmax, __shfl_xor(tmax, 8));
        float mnew = fmaxf(mrun[r], tmax);
        float sc = __expf(mrun[r] - mnew);
        mrun[r] = mnew;
        float pv = __expf(sv - mnew);
        lpart[r] = lpart[r] * sc + pv;
        oacc[0][r] *= sc; oacc[1][r] *= sc; oacc[2][r] *= sc; oacc[3][r] *= sc;
        pbuf[hd][(lhi << 2) + r][l15] = f2bf(pv);
      }
      __syncthreads();   // per-wave P region; barrier guarantees write->read order
      bf16x8 pa;
      union { bf16x8 v; uint4 q; } pz;
      if (lhi < 2){
        pa = *(const bf16x8*)(&pbuf[hd][l15][lhi << 3]);  // A row t=l15, k=t'
      } else {
        pz.q = make_uint4(0,0,0,0);  // zero-pad k = 16..31
        pa = pz.v;
      }
      const int vm = sb + ((lhi & 1) << 3);
      #pragma unroll
      for (int c = 0; c < 4; ++c){
        const size_t voff = ((size_t)(hd*HD_ + c*16 + l15) << 14) + vm;
        bf16x8 vb = *(const bf16x8*)(vt + voff);          // B k=t', col d
        oacc[c] = __builtin_amdgcn_mfma_f32_16x16x32_bf16(pa, vb, oacc[c], 0, 0, 0);
      }
    }
  }

  #pragma unroll
  for (int r = 0; r < 4; ++r){
    float ls = lpart[r];
    ls += __shfl_xor(ls, 1);
    ls += __shfl_xor(ls, 2);
    ls += __shfl_xor(ls, 4);
    ls += __shfl_xor(ls, 8);
    float inv = 1.0f / ls;
    int t = (lhi << 2) + r;
    size_t row = ((size_t)hw * 16 + t) * CC + hd * HD_;
    #pragma unroll
    for (int c = 0; c < 4; ++c)
      ao[row + c*16 + l15] = f2bf(oacc[c][r] * inv);
  }
}

// ---------------------------------------------------------------------------
extern "C" void kernel_launch(void* const* d_in, const int* in_sizes, int n_in,
                              void* d_out, int out_size, void* d_ws, size_t ws_size,
                              hipStream_t stream){
  const float* x  = (const float*)d_in[0];
  const float* wq = (const float*)d_in[1];
  const float* wk = (const float*)d_in[2];
  const float* wv = (const float*)d_in[3];
  const float* wo = (const float*)d_in[4];
  const float* bo = (const float*)d_in[5];

  char* ws = (char*)d_ws;
  u16* Xb  = (u16*)(ws);                    // 16,777,216 B
  u16* Wt  = (u16*)(ws + 16777216);         //  1,572,864 B
  u16* Wot = (u16*)(ws + 18350080);         //    524,288 B
  u16* QKV = (u16*)(ws + 18874368);         // 50,331,648 B
  u16* Vt  = (u16*)(ws + 69206016);         // 16,777,216 B
  u16* AO  = (u16*)(ws + 85983232);         // 16,777,216 B  (total 102,760,448)

  k_convert_x<<<4096, 256, 0, stream>>>(x, Xb);
  k_convert_w<<<4096, 256, 0, stream>>>(wq, wk, wv, wo, Wt, Wot);
  { dim3 g(12, 128); k_gemm_bt<0><<<g, 256, 0, stream>>>(Xb, Wt, QKV, nullptr, 16384, 1536, 512); }
  { dim3 g(8, 256);  k_vt<<<g, 256, 0, stream>>>(QKV, Vt); }
  k_attn<<<1024, 512, 0, stream>>>(QKV, Vt, AO);
  { dim3 g(4, 128);  k_gemm_bt<1><<<g, 256, 0, stream>>>(AO, Wot, (float*)d_out, bo, 16384, 512, 512); }
}

// Round 4
// 340.814 us; speedup vs baseline: 1.4626x; 1.4626x over previous
//
#include <hip/hip_runtime.h>

typedef unsigned int u32;
typedef unsigned short u16;
typedef __attribute__((ext_vector_type(8))) __bf16 bf16x8;
typedef __attribute__((ext_vector_type(4))) float f32x4;
typedef __attribute__((ext_vector_type(2))) unsigned int u32x2;

#define T_   16
#define HH   32
#define WW   32
#define HEADS_ 8
#define HD_  64
#define CC   512
#define NPOS 16384
#define CQKV 1536

__device__ __forceinline__ u16 f2bf(float f){
  u32 u = __builtin_bit_cast(u32, f);
  u32 r = u + 0x7FFFu + ((u >> 16) & 1u);
  return (u16)(r >> 16);
}

__device__ __forceinline__ u32 cvt_pk_bf16(float lo, float hi){
  u32 r;
  asm("v_cvt_pk_bf16_f32 %0, %1, %2" : "=v"(r) : "v"(lo), "v"(hi));
  return r;
}

__device__ __forceinline__ void gload16(const void* g, void* l){
  __builtin_amdgcn_global_load_lds(
    (const __attribute__((address_space(1))) void*)g,
    (__attribute__((address_space(3))) void*)l, 16, 0, 0);
}

// ---- convert x (fp32 -> bf16), 8 elems/thread -------------------------------
__global__ __launch_bounds__(256) void k_convert_x(const float* __restrict__ x,
                                                   u16* __restrict__ xb){
  int i = blockIdx.x * 256 + threadIdx.x;
  const float4 a = ((const float4*)x)[i*2];
  const float4 b = ((const float4*)x)[i*2+1];
  union { u16 h[8]; uint4 q; } o;
  o.h[0]=f2bf(a.x); o.h[1]=f2bf(a.y); o.h[2]=f2bf(a.z); o.h[3]=f2bf(a.w);
  o.h[4]=f2bf(b.x); o.h[5]=f2bf(b.y); o.h[6]=f2bf(b.z); o.h[7]=f2bf(b.w);
  ((uint4*)xb)[i] = o.q;
}

// ---- weights: Wt[n][k] = w_*[k][n&511] (qkv concat), Wot[n][k] = w_o[k][n] --
__global__ __launch_bounds__(256) void k_convert_w(const float* __restrict__ wq,
                                                   const float* __restrict__ wk,
                                                   const float* __restrict__ wv,
                                                   const float* __restrict__ wo,
                                                   u16* __restrict__ wt,
                                                   u16* __restrict__ wot){
  int i = blockIdx.x * 256 + threadIdx.x;
  if (i < 1536*512){
    int n = i >> 9, k = i & 511;
    const float* src = (n < 512) ? wq : (n < 1024) ? wk : wv;
    wt[i] = f2bf(src[k*512 + (n & 511)]);
  } else {
    int j = i - 1536*512;
    int n = j >> 9, k = j & 511;
    wot[j] = f2bf(wo[k*512 + n]);
  }
}

// ---- bf16 MFMA GEMM, A[M,K] x Bt[N,K]^T -> C[M,N]. 128x128 tile, BK=32 ------
template<int OUTMODE>
__global__ __launch_bounds__(256) void k_gemm_bt(
    const u16* __restrict__ A, const u16* __restrict__ Bt,
    void* __restrict__ C, const float* __restrict__ bias,
    int M, int N, int K)
{
  __shared__ u16 lds[2][2][128*32];
  const int tid = threadIdx.x;
  const int lane = tid & 63;
  const int l15 = lane & 15, lhi = lane >> 4;
  const int wv = tid >> 6;
  const int tm = blockIdx.y * 128, tn = blockIdx.x * 128;
  const int wm = (wv >> 1) * 64, wn = (wv & 1) * 64;
  const int nk = K >> 5;

  auto stage = [&](int buf, int kb){
    #pragma unroll
    for (int half = 0; half < 2; ++half){
      int c = tid + half*256;
      int row = c >> 2;
      int g = (c & 3) ^ ((c >> 3) & 3);
      char* la = (char*)(&lds[buf][0][0]) + ((c >> 6) << 10);
      gload16(A + (size_t)(tm + row) * K + (kb << 5) + (g << 3), la);
      char* lb = (char*)(&lds[buf][1][0]) + ((c >> 6) << 10);
      gload16(Bt + (size_t)(tn + row) * K + (kb << 5) + (g << 3), lb);
    }
  };

  stage(0, 0);
  f32x4 acc[4][4];
  const f32x4 z4 = {0.f, 0.f, 0.f, 0.f};
  #pragma unroll
  for (int i = 0; i < 4; ++i)
    #pragma unroll
    for (int j = 0; j < 4; ++j) acc[i][j] = z4;
  __syncthreads();

  int buf = 0;
  for (int kb = 0; kb < nk; ++kb){
    if (kb + 1 < nk) stage(buf ^ 1, kb + 1);
    const char* la = (const char*)(&lds[buf][0][0]);
    const char* lb = (const char*)(&lds[buf][1][0]);
    bf16x8 af[4], bfr[4];
    #pragma unroll
    for (int ai = 0; ai < 4; ++ai){
      int row = wm + ai*16 + l15;
      af[ai] = *(const bf16x8*)(la + row*64 + ((lhi ^ ((row >> 1) & 3)) << 4));
    }
    #pragma unroll
    for (int bj = 0; bj < 4; ++bj){
      int row = wn + bj*16 + l15;
      bfr[bj] = *(const bf16x8*)(lb + row*64 + ((lhi ^ ((row >> 1) & 3)) << 4));
    }
    #pragma unroll
    for (int ai = 0; ai < 4; ++ai)
      #pragma unroll
      for (int bj = 0; bj < 4; ++bj)
        acc[ai][bj] = __builtin_amdgcn_mfma_f32_16x16x32_bf16(af[ai], bfr[bj], acc[ai][bj], 0, 0, 0);
    __syncthreads();
    buf ^= 1;
  }

  #pragma unroll
  for (int ai = 0; ai < 4; ++ai)
    #pragma unroll
    for (int bj = 0; bj < 4; ++bj)
      #pragma unroll
      for (int r = 0; r < 4; ++r){
        int rr = tm + wm + ai*16 + (lhi << 2) + r;
        int cc = tn + wn + bj*16 + l15;
        float v = acc[ai][bj][r];
        if (OUTMODE == 0) ((u16*)C)[(size_t)rr * N + cc] = f2bf(v);
        else              ((float*)C)[(size_t)rr * N + cc] = v + bias[cc];
      }
}

// ---- V^T: Vt[ch][m] = QKV[m][1024+ch], tiled 64x64 transpose ----------------
__global__ __launch_bounds__(256) void k_vt(const u16* __restrict__ qkv,
                                            u16* __restrict__ vt){
  __shared__ u16 tl[64][65];
  const int tid = threadIdx.x;
  const int m0 = blockIdx.y << 6, c0 = blockIdx.x << 6;
  #pragma unroll
  for (int i = 0; i < 16; ++i){
    int idx = tid + (i << 8);
    int r = idx >> 6, c = idx & 63;
    tl[r][c] = qkv[(size_t)(m0 + r) * CQKV + 1024 + c0 + c];
  }
  __syncthreads();
  #pragma unroll
  for (int i = 0; i < 16; ++i){
    int idx = tid + (i << 8);
    int d = idx >> 6, mm = idx & 63;
    vt[((size_t)(c0 + d) << 14) + m0 + mm] = tl[mm][d];
  }
}

// ---- neighborhood attention -------------------------------------------------
// Block = 256 thr (4 waves); wave = 1 head; 2 blocks per (h,w).
// QK (swapped, verified 16x16x32 mappings): S^T = mfma(K_A, Q_B) ->
//   lane holds S[t=l15][t'=lhi*4+r], r=0..3. Softmax in the t=l15 frame.
// PV (round-1-verified): P staged through per-wave LDS tile (ds_write_b64),
//   read back as zero-padded 16x16x32 A-frag; V as B-frag from Vt.
//   oacc: O[t=lhi*4+r][d_sub=l15] per 16-channel block c.
__global__ __launch_bounds__(256) void k_attn(const u16* __restrict__ qkv,
                                              const u16* __restrict__ vt,
                                              u16* __restrict__ ao){
  __shared__ __align__(16) u16 pbuf[4][7][16][16];
  const int tid = threadIdx.x;
  const int lane = tid & 63;
  const int wv = tid >> 6;
  const int l15 = lane & 15, lhi = lane >> 4;
  const int bid = blockIdx.x;
  const int swz = (bid & 7) * 256 + (bid >> 3);      // XCD-contiguous, bijective (2048=8*256)
  const int hw = swz >> 1;
  const int head = ((swz & 1) << 2) + wv;
  const int h = hw >> 5, w = hw & 31;
  const int hs = min(max(h - 3, 0), HH - 7);
  const int ws = min(max(w - 3, 0), WW - 7);

  // Q as B-frag: col t = l15, k = d = lhi*8+j (and +32)
  const size_t qoff = ((size_t)hw * 16 + l15) * CQKV + head * HD_ + (lhi << 3);
  const bf16x8 qb0 = *(const bf16x8*)(qkv + qoff);
  const bf16x8 qb1 = *(const bf16x8*)(qkv + qoff + 32);

  // t-window mask: col t = l15, rows t' = lhi*4+r
  const int tst = min(max(l15 - 3, 0), T_ - 7);
  bool val[4];
  #pragma unroll
  for (int r = 0; r < 4; ++r){
    int tp = (lhi << 2) + r;
    val[r] = (tp >= tst) && (tp < tst + 7);
  }

  float mrun = -3.0e38f, lp = 0.f;
  f32x4 oacc[4];
  const f32x4 z4 = {0.f,0.f,0.f,0.f};
  #pragma unroll
  for (int c = 0; c < 4; ++c) oacc[c] = z4;

  for (int jh = 0; jh < 7; ++jh){
    const int rowb = ((hs + jh) << 5) + ws;
    // K A-frags for 7 offsets: row t'=l15, k=d
    bf16x8 ka0[7], ka1[7];
    #pragma unroll
    for (int s = 0; s < 7; ++s){
      const size_t koff = ((size_t)(((rowb + s) << 4) + l15)) * CQKV + CC + head * HD_ + (lhi << 3);
      ka0[s] = *(const bf16x8*)(qkv + koff);
      ka1[s] = *(const bf16x8*)(qkv + koff + 32);
    }
    f32x4 st[7];
    #pragma unroll
    for (int s = 0; s < 7; ++s){
      f32x4 acc = z4;
      acc = __builtin_amdgcn_mfma_f32_16x16x32_bf16(ka0[s], qb0, acc, 0, 0, 0);
      acc = __builtin_amdgcn_mfma_f32_16x16x32_bf16(ka1[s], qb1, acc, 0, 0, 0);
      st[s] = acc;
    }
    // mask + tile max
    float tmax = -3.0e38f;
    #pragma unroll
    for (int s = 0; s < 7; ++s)
      #pragma unroll
      for (int r = 0; r < 4; ++r){
        float sv = val[r] ? st[s][r] : -1.0e30f;
        st[s][r] = sv;
        tmax = fmaxf(tmax, sv);
      }
    tmax = fmaxf(tmax, __shfl_xor(tmax, 16));
    tmax = fmaxf(tmax, __shfl_xor(tmax, 32));
    const float mnew = fmaxf(mrun, tmax);
    const float sc = __expf(mrun - mnew);
    mrun = mnew;
    lp *= sc;
    // redistribute sc from t=l15 frame to t=lhi*4+r frame (lanes 0..15 hold t=0..15)
    float scr[4];
    #pragma unroll
    for (int r = 0; r < 4; ++r) scr[r] = __shfl(sc, (lhi << 2) + r);
    #pragma unroll
    for (int c = 0; c < 4; ++c)
      #pragma unroll
      for (int r = 0; r < 4; ++r) oacc[c][r] *= scr[r];
    // P = exp(S - m); lane owns P[t=l15][t'=lhi*4+0..3] -> contiguous b64 store
    #pragma unroll
    for (int s = 0; s < 7; ++s){
      float p0 = __expf(st[s][0] - mnew);
      float p1 = __expf(st[s][1] - mnew);
      float p2 = __expf(st[s][2] - mnew);
      float p3 = __expf(st[s][3] - mnew);
      lp += (p0 + p1) + (p2 + p3);
      u32x2 pw;
      pw.x = cvt_pk_bf16(p0, p1);
      pw.y = cvt_pk_bf16(p2, p3);
      *(u32x2*)(&pbuf[wv][s][l15][lhi << 2]) = pw;
    }
    // same-wave LDS write->read: lgkmcnt drain + compiler fence (no block barrier)
    asm volatile("s_waitcnt lgkmcnt(0)" ::: "memory");
    __builtin_amdgcn_sched_barrier(0);
    // PV: verified zero-padded 16x16x32 path
    #pragma unroll
    for (int s = 0; s < 7; ++s){
      bf16x8 pa;
      if (lhi < 2){
        pa = *(const bf16x8*)(&pbuf[wv][s][l15][lhi << 3]);  // row t=l15, k=t'=lhi*8+j
      } else {
        union { bf16x8 v; uint4 q; } pz;
        pz.q = make_uint4(0,0,0,0);
        pa = pz.v;   // zero-pad k = 16..31
      }
      const int vm = ((rowb + s) << 4) + ((lhi & 1) << 3);
      #pragma unroll
      for (int c = 0; c < 4; ++c){
        const size_t voff = ((size_t)(head * HD_ + c * 16 + l15) << 14) + vm;
        bf16x8 vb = *(const bf16x8*)(vt + voff);             // B: k=t', col d_sub=l15
        oacc[c] = __builtin_amdgcn_mfma_f32_16x16x32_bf16(pa, vb, oacc[c], 0, 0, 0);
      }
    }
    asm volatile("" ::: "memory");   // pin LDS reads before next jh's writes
  }

  float lsum = lp;
  lsum += __shfl_xor(lsum, 16);
  lsum += __shfl_xor(lsum, 32);
  const float inv = 1.0f / lsum;

  #pragma unroll
  for (int r = 0; r < 4; ++r){
    const float invr = __shfl(inv, (lhi << 2) + r);   // 1/lsum for t=lhi*4+r
    const int t = (lhi << 2) + r;
    const size_t row = ((size_t)hw * 16 + t) * CC + head * HD_;
    #pragma unroll
    for (int c = 0; c < 4; ++c)
      ao[row + c*16 + l15] = f2bf(oacc[c][r] * invr);
  }
}

// ---------------------------------------------------------------------------
extern "C" void kernel_launch(void* const* d_in, const int* in_sizes, int n_in,
                              void* d_out, int out_size, void* d_ws, size_t ws_size,
                              hipStream_t stream){
  const float* x  = (const float*)d_in[0];
  const float* wq = (const float*)d_in[1];
  const float* wk = (const float*)d_in[2];
  const float* wv = (const float*)d_in[3];
  const float* wo = (const float*)d_in[4];
  const float* bo = (const float*)d_in[5];

  char* ws = (char*)d_ws;
  u16* Xb  = (u16*)(ws);                    // 16,777,216 B
  u16* Wt  = (u16*)(ws + 16777216);         //  1,572,864 B
  u16* Wot = (u16*)(ws + 18350080);         //    524,288 B
  u16* QKV = (u16*)(ws + 18874368);         // 50,331,648 B
  u16* Vt  = (u16*)(ws + 69206016);         // 16,777,216 B
  u16* AO  = (u16*)(ws + 85983232);         // 16,777,216 B

  k_convert_x<<<4096, 256, 0, stream>>>(x, Xb);
  k_convert_w<<<4096, 256, 0, stream>>>(wq, wk, wv, wo, Wt, Wot);
  { dim3 g(12, 128); k_gemm_bt<0><<<g, 256, 0, stream>>>(Xb, Wt, QKV, nullptr, 16384, 1536, 512); }
  { dim3 g(8, 256);  k_vt<<<g, 256, 0, stream>>>(QKV, Vt); }
  k_attn<<<2048, 256, 0, stream>>>(QKV, Vt, AO);
  { dim3 g(4, 128);  k_gemm_bt<1><<<g, 256, 0, stream>>>(AO, Wot, (float*)d_out, bo, 16384, 512, 512); }
}